// Round 2
// baseline (1165.766 us; speedup 1.0000x reference)
//
#include <hip/hip_runtime.h>
#include <math.h>

#define NROWS 16384
#define DM    2048
#define RK    16
#define LRc    1e-3f
#define L2c    1e-4f
#define MOMc   0.9f
#define SCALEc 0.1f
#define LNEPS  1e-5f

// ---------------------------------------------------------------------------
// k_A: per-row rank-16 reductions over d:
//   kC[n,r]  = sum_d k[n,d] C[d,r]
//   vB[r]    = sum_d v[n,d] B[d,r]          (not stored)
//   kDB[r]   = sum_d k[n,d] D[d] B[d,r]     (skipped when D==0)
//   errB[n,r] = vB - kDB - 0.1 * sum_s kC[s] BtB[s,r]   (analytic, in-wave)
//   G2[d,r] += k[n,d] * errB[n,r]           (register accumulators, atomic flush)
//   colsum[d] += k[n,d]
// 256 blocks x 512 threads; block = 64 rows; thread owns 4 d-columns.
// ---------------------------------------------------------------------------
__global__ __launch_bounds__(512, 2) void k_A(
    const float* __restrict__ k, const float* __restrict__ v,
    const float* __restrict__ B, const float* __restrict__ C,
    const float* __restrict__ Dd, const float* __restrict__ BtB,
    float* __restrict__ kC_g, float* __restrict__ G2, float* __restrict__ colsum)
{
    __shared__ float p_lds[512][52];    // 52-pad: 13x16B rows, stride coprime with 8 bank-quads
    __shared__ float s1[8][64];
    __shared__ float kCsh[16], errBsh[16];
    __shared__ float BtBsh[256];
    __shared__ int   dflag_sh;

    const int t  = threadIdx.x;
    const int d0 = t * 4;
    const int row0 = blockIdx.x * 64;

    float Breg[4][16], Creg[4][16], Dreg[4];
    #pragma unroll
    for (int i = 0; i < 4; ++i) {
        #pragma unroll
        for (int q = 0; q < 4; ++q) {
            float4 b4 = *(const float4*)(B + (size_t)(d0 + i) * RK + q * 4);
            float4 c4 = *(const float4*)(C + (size_t)(d0 + i) * RK + q * 4);
            Breg[i][q*4+0] = b4.x; Breg[i][q*4+1] = b4.y;
            Breg[i][q*4+2] = b4.z; Breg[i][q*4+3] = b4.w;
            Creg[i][q*4+0] = c4.x; Creg[i][q*4+1] = c4.y;
            Creg[i][q*4+2] = c4.z; Creg[i][q*4+3] = c4.w;
        }
        Dreg[i] = Dd[d0 + i];
    }

    if (t == 0) dflag_sh = 0;
    if (t < 64) *(float4*)&BtBsh[t * 4] = *(const float4*)&BtB[t * 4];
    __syncthreads();
    if (Dreg[0] != 0.f || Dreg[1] != 0.f || Dreg[2] != 0.f || Dreg[3] != 0.f)
        dflag_sh = 1;
    __syncthreads();
    const int dnz = dflag_sh;
    if (!dnz) {   // kDB columns are identically zero; zero once, never rewrite
        *(float4*)&p_lds[t][32] = make_float4(0.f,0.f,0.f,0.f);
        *(float4*)&p_lds[t][36] = make_float4(0.f,0.f,0.f,0.f);
        *(float4*)&p_lds[t][40] = make_float4(0.f,0.f,0.f,0.f);
        *(float4*)&p_lds[t][44] = make_float4(0.f,0.f,0.f,0.f);
    }

    float g2[4][16];
    #pragma unroll
    for (int i = 0; i < 4; ++i)
        #pragma unroll
        for (int r = 0; r < 16; ++r) g2[i][r] = 0.f;
    float cs[4] = {0.f, 0.f, 0.f, 0.f};

    float4 k4 = *(const float4*)(k + (size_t)row0 * DM + d0);
    float4 v4 = *(const float4*)(v + (size_t)row0 * DM + d0);

    for (int rr = 0; rr < 64; ++rr) {
        const int n = row0 + rr;
        const float ka[4] = {k4.x, k4.y, k4.z, k4.w};
        const float va[4] = {v4.x, v4.y, v4.z, v4.w};

        const int nn = row0 + ((rr < 63) ? rr + 1 : rr);
        float4 k4n = *(const float4*)(k + (size_t)nn * DM + d0);
        float4 v4n = *(const float4*)(v + (size_t)nn * DM + d0);

        // ---- partials (staggered groups to cap live registers) ----
        {
            float pk[16];
            #pragma unroll
            for (int r = 0; r < 16; ++r)
                pk[r] = ka[0]*Creg[0][r] + ka[1]*Creg[1][r]
                      + ka[2]*Creg[2][r] + ka[3]*Creg[3][r];
            *(float4*)&p_lds[t][0]  = make_float4(pk[0],  pk[1],  pk[2],  pk[3]);
            *(float4*)&p_lds[t][4]  = make_float4(pk[4],  pk[5],  pk[6],  pk[7]);
            *(float4*)&p_lds[t][8]  = make_float4(pk[8],  pk[9],  pk[10], pk[11]);
            *(float4*)&p_lds[t][12] = make_float4(pk[12], pk[13], pk[14], pk[15]);
        }
        __builtin_amdgcn_sched_barrier(0);
        {
            float pv[16];
            #pragma unroll
            for (int r = 0; r < 16; ++r)
                pv[r] = va[0]*Breg[0][r] + va[1]*Breg[1][r]
                      + va[2]*Breg[2][r] + va[3]*Breg[3][r];
            *(float4*)&p_lds[t][16] = make_float4(pv[0],  pv[1],  pv[2],  pv[3]);
            *(float4*)&p_lds[t][20] = make_float4(pv[4],  pv[5],  pv[6],  pv[7]);
            *(float4*)&p_lds[t][24] = make_float4(pv[8],  pv[9],  pv[10], pv[11]);
            *(float4*)&p_lds[t][28] = make_float4(pv[12], pv[13], pv[14], pv[15]);
        }
        __builtin_amdgcn_sched_barrier(0);
        if (dnz) {
            const float kd[4] = {ka[0]*Dreg[0], ka[1]*Dreg[1], ka[2]*Dreg[2], ka[3]*Dreg[3]};
            float pd[16];
            #pragma unroll
            for (int r = 0; r < 16; ++r)
                pd[r] = kd[0]*Breg[0][r] + kd[1]*Breg[1][r]
                      + kd[2]*Breg[2][r] + kd[3]*Breg[3][r];
            *(float4*)&p_lds[t][32] = make_float4(pd[0],  pd[1],  pd[2],  pd[3]);
            *(float4*)&p_lds[t][36] = make_float4(pd[4],  pd[5],  pd[6],  pd[7]);
            *(float4*)&p_lds[t][40] = make_float4(pd[8],  pd[9],  pd[10], pd[11]);
            *(float4*)&p_lds[t][44] = make_float4(pd[12], pd[13], pd[14], pd[15]);
        }
        cs[0] += ka[0]; cs[1] += ka[1]; cs[2] += ka[2]; cs[3] += ka[3];
        __syncthreads();

        // ---- stage1: 8 groups x 64 rows each ----
        {
            const int col = t & 63, grp = t >> 6;
            if (col < 48) {
                float s = 0.f;
                #pragma unroll
                for (int i = 0; i < 64; ++i) s += p_lds[grp * 64 + i][col];
                s1[grp][col] = s;
            }
        }
        __syncthreads();

        // ---- stage2 + errB: wave 0 only, finished with shuffles ----
        if (t < 64) {
            float rv = 0.f;
            if (t < 48) {
                #pragma unroll
                for (int g = 0; g < 8; ++g) rv += s1[g][t];
            }
            // acc = sum_s kC[s] * BtB[s][r], r = t&15   (kC lives in lanes 0..15)
            float acc = 0.f;
            #pragma unroll
            for (int s = 0; s < 16; ++s) {
                const float kcs = __shfl(rv, s);
                acc += kcs * BtBsh[s * 16 + (t & 15)];
            }
            const float kdbv = __shfl(rv, (t & 15) + 32);
            if (t < 16) {
                kCsh[t] = rv;
            } else if (t < 32) {
                errBsh[t - 16] = rv - kdbv - SCALEc * acc;
            }
        }
        __syncthreads();

        // ---- G2 accumulation (same row: uses ka) + kC global write ----
        {
            float eb[16];
            #pragma unroll
            for (int q = 0; q < 4; ++q) {
                const float4 e4 = *(const float4*)&errBsh[q * 4];
                eb[q*4+0] = e4.x; eb[q*4+1] = e4.y; eb[q*4+2] = e4.z; eb[q*4+3] = e4.w;
            }
            #pragma unroll
            for (int r = 0; r < 16; ++r) {
                g2[0][r] += ka[0] * eb[r];
                g2[1][r] += ka[1] * eb[r];
                g2[2][r] += ka[2] * eb[r];
                g2[3][r] += ka[3] * eb[r];
            }
        }
        if (t < 4) {
            const float4 kcv = *(const float4*)&kCsh[t * 4];
            *(float4*)(kC_g + (size_t)n * RK + t * 4) = kcv;
        }

        k4 = k4n; v4 = v4n;
    }

    #pragma unroll
    for (int i = 0; i < 4; ++i) atomicAdd(colsum + d0 + i, cs[i]);
    #pragma unroll
    for (int i = 0; i < 4; ++i)
        #pragma unroll
        for (int r = 0; r < 16; ++r)
            atomicAdd(G2 + (size_t)(d0 + i) * RK + r, g2[i][r]);
}

// ---------------------------------------------------------------------------
// k_B: pure streaming pass, no cross-thread reductions:
//   ro[n,d] = 0.1 * kC[n,:].B[d,:] + k[n,d]*D[d]
//   err     = v - ro
//   G1[d,r] += err[n,d] * kC[n,r]    (register accumulators, atomic flush)
// grid = 2 d-slabs x 256 chunks (64 rows); 256 threads, thread owns 4 d.
// kC chunk staged in LDS (4 KB); 2-row-deep float4 prefetch.
// ---------------------------------------------------------------------------
__global__ __launch_bounds__(256, 2) void k_B(
    const float* __restrict__ k, const float* __restrict__ v,
    const float* __restrict__ B, const float* __restrict__ Dd,
    const float* __restrict__ kC_g,
    float* __restrict__ ro, float* __restrict__ G1)
{
    __shared__ float kCch[64 * 16];   // 4 KB

    const int t = threadIdx.x;
    const int slab = blockIdx.x & 1;
    const int chunk = blockIdx.x >> 1;
    const int d0 = slab * 1024 + t * 4;
    const int row0 = chunk * 64;

    float Breg[4][16], Dreg[4];
    #pragma unroll
    for (int i = 0; i < 4; ++i) {
        #pragma unroll
        for (int q = 0; q < 4; ++q) {
            float4 b4 = *(const float4*)(B + (size_t)(d0 + i) * RK + q * 4);
            Breg[i][q*4+0] = b4.x; Breg[i][q*4+1] = b4.y;
            Breg[i][q*4+2] = b4.z; Breg[i][q*4+3] = b4.w;
        }
        Dreg[i] = Dd[d0 + i];
    }

    // stage the chunk's kC rows (64 x 16 floats)
    *(float4*)&kCch[t * 4] = *(const float4*)(kC_g + (size_t)row0 * RK + t * 4);
    __syncthreads();

    float g1[4][16];
    #pragma unroll
    for (int i = 0; i < 4; ++i)
        #pragma unroll
        for (int r = 0; r < 16; ++r) g1[i][r] = 0.f;

    // 2-deep prefetch
    float4 kA = *(const float4*)(k + (size_t)row0 * DM + d0);
    float4 vA = *(const float4*)(v + (size_t)row0 * DM + d0);
    float4 kB2 = *(const float4*)(k + (size_t)(row0 + 1) * DM + d0);
    float4 vB2 = *(const float4*)(v + (size_t)(row0 + 1) * DM + d0);

    for (int rr = 0; rr < 64; ++rr) {
        const int n = row0 + rr;
        const float ka[4] = {kA.x, kA.y, kA.z, kA.w};
        const float va[4] = {vA.x, vA.y, vA.z, vA.w};

        const int np = row0 + ((rr < 62) ? rr + 2 : 63);
        float4 kN = *(const float4*)(k + (size_t)np * DM + d0);
        float4 vN = *(const float4*)(v + (size_t)np * DM + d0);

        float kc[16];
        {
            const float* kcr = &kCch[rr * 16];
            #pragma unroll
            for (int q = 0; q < 4; ++q) {
                const float4 c4 = *(const float4*)(kcr + q * 4);
                kc[q*4+0] = c4.x; kc[q*4+1] = c4.y; kc[q*4+2] = c4.z; kc[q*4+3] = c4.w;
            }
        }

        float roa[4], err[4];
        #pragma unroll
        for (int i = 0; i < 4; ++i) {
            float s = 0.f;
            #pragma unroll
            for (int r = 0; r < 16; ++r) s += kc[r] * Breg[i][r];
            roa[i] = SCALEc * s + ka[i] * Dreg[i];
            err[i] = va[i] - roa[i];
        }
        *(float4*)(ro + (size_t)n * DM + d0) = make_float4(roa[0], roa[1], roa[2], roa[3]);

        #pragma unroll
        for (int r = 0; r < 16; ++r) {
            g1[0][r] += err[0] * kc[r];
            g1[1][r] += err[1] * kc[r];
            g1[2][r] += err[2] * kc[r];
            g1[3][r] += err[3] * kc[r];
        }

        kA = kB2; vA = vB2; kB2 = kN; vB2 = vN;
    }

    #pragma unroll
    for (int i = 0; i < 4; ++i)
        #pragma unroll
        for (int r = 0; r < 16; ++r)
            atomicAdd(G1 + (size_t)(d0 + i) * RK + r, g1[i][r]);
}

// ---------------------------------------------------------------------------
// k_ctc: CtC = C^T C, BtB = B^T B  (16x16 each). 16 blocks x 256 threads.
// Must run BEFORE k_A (k_A consumes BtB).
// ---------------------------------------------------------------------------
__global__ __launch_bounds__(256) void k_ctc(
    const float* __restrict__ B, const float* __restrict__ C,
    float* __restrict__ BtB, float* __restrict__ CtC)
{
    const int t = threadIdx.x;
    const int a = t >> 4, b = t & 15;
    const int dBeg = blockIdx.x * 128;
    float sc = 0.f, sb = 0.f;
    for (int d = dBeg; d < dBeg + 128; ++d) {
        sc += C[d * RK + a] * C[d * RK + b];
        sb += B[d * RK + a] * B[d * RK + b];
    }
    atomicAdd(CtC + a * RK + b, sc);
    atomicAdd(BtB + a * RK + b, sb);
}

// ---------------------------------------------------------------------------
// k_ln: k_mean = colsum/N; h1 = LayerNorm(k_mean)*gamma + beta. One block x256.
// ---------------------------------------------------------------------------
__global__ __launch_bounds__(256) void k_ln(
    const float* __restrict__ colsum,
    const float* __restrict__ gam, const float* __restrict__ bet,
    float* __restrict__ h1)
{
    __shared__ float red[256];
    __shared__ float mu_sh, var_sh;
    const int t = threadIdx.x;
    float x[8];
    float s = 0.f;
    #pragma unroll
    for (int i = 0; i < 8; ++i) {
        x[i] = colsum[t + 256 * i] * (1.0f / (float)NROWS);
        s += x[i];
    }
    red[t] = s; __syncthreads();
    for (int off = 128; off > 0; off >>= 1) {
        if (t < off) red[t] += red[t + off];
        __syncthreads();
    }
    if (t == 0) mu_sh = red[0] * (1.0f / (float)DM);
    __syncthreads();
    const float mu = mu_sh;
    float s2 = 0.f;
    #pragma unroll
    for (int i = 0; i < 8; ++i) { const float dd = x[i] - mu; s2 += dd * dd; }
    __syncthreads();
    red[t] = s2; __syncthreads();
    for (int off = 128; off > 0; off >>= 1) {
        if (t < off) red[t] += red[t + off];
        __syncthreads();
    }
    if (t == 0) var_sh = red[0] * (1.0f / (float)DM);
    __syncthreads();
    const float rstd = rsqrtf(var_sh + LNEPS);
    #pragma unroll
    for (int i = 0; i < 8; ++i) {
        const int d = t + 256 * i;
        h1[d] = (x[i] - mu) * rstd * gam[d] + bet[d];
    }
}

// ---------------------------------------------------------------------------
// k_gemv: h2[i] = silu(h1 . W1[i,:] + b1[i]). 512 blocks x 256 (wave/row).
// ---------------------------------------------------------------------------
__global__ __launch_bounds__(256) void k_gemv(
    const float* __restrict__ h1, const float* __restrict__ W1,
    const float* __restrict__ b1, float* __restrict__ h2)
{
    const int t = threadIdx.x;
    const int lane = t & 63;
    const int w = t >> 6;
    const int row = blockIdx.x * 4 + w;
    const float* wr = W1 + (size_t)row * DM;
    float s = 0.f;
    #pragma unroll
    for (int j = 0; j < 8; ++j) {
        const float4 a = *(const float4*)(wr + j * 256 + lane * 4);
        const float4 b = *(const float4*)(h1 + j * 256 + lane * 4);
        s += a.x * b.x + a.y * b.y + a.z * b.z + a.w * b.w;
    }
    #pragma unroll
    for (int off = 32; off > 0; off >>= 1) s += __shfl_down(s, off);
    if (lane == 0) {
        const float val = s + b1[row];
        h2[row] = val / (1.0f + expf(-val));   // silu
    }
}

// ---------------------------------------------------------------------------
// k_alpha: alpha = sigmoid(h2 . W2 + b2). One block x 256.
// ---------------------------------------------------------------------------
__global__ __launch_bounds__(256) void k_alpha(
    const float* __restrict__ h2, const float* __restrict__ W2,
    const float* __restrict__ b2,
    float* __restrict__ alpha_ws, float* __restrict__ out_alpha)
{
    __shared__ float red[256];
    const int t = threadIdx.x;
    float s = 0.f;
    for (int i = t; i < DM; i += 256) s += h2[i] * W2[i];
    red[t] = s; __syncthreads();
    for (int off = 128; off > 0; off >>= 1) {
        if (t < off) red[t] += red[t + off];
        __syncthreads();
    }
    if (t == 0) {
        const float logit = red[0] + b2[0];
        const float a = 1.0f / (1.0f + expf(-logit));
        alpha_ws[0] = a;
        out_alpha[0] = a;
    }
}

// ---------------------------------------------------------------------------
// k_update: gradB/gradC -> S_B_new/S_C_new -> B_new/C_new. 128 blocks x 256.
//   W@C   ~= SCALE*B(CtC) + D o C
//   W^T@B ~= SCALE*C(BtB) + D o B
// ---------------------------------------------------------------------------
__global__ __launch_bounds__(256) void k_update(
    const float* __restrict__ B, const float* __restrict__ C,
    const float* __restrict__ Dd,
    const float* __restrict__ S_B, const float* __restrict__ S_C,
    const float* __restrict__ G1, const float* __restrict__ G2,
    const float* __restrict__ CtC, const float* __restrict__ BtB,
    const float* __restrict__ alpha_ws,
    float* __restrict__ outB, float* __restrict__ outC,
    float* __restrict__ outSB, float* __restrict__ outSC)
{
    const int idx = blockIdx.x * 256 + threadIdx.x;   // [0, 32768)
    const int d = idx >> 4, r = idx & 15;
    const float alpha = alpha_ws[0];

    float Brow[16], Crow[16];
    #pragma unroll
    for (int q = 0; q < 4; ++q) {
        const float4 b4 = *(const float4*)(B + (size_t)d * RK + q * 4);
        const float4 c4 = *(const float4*)(C + (size_t)d * RK + q * 4);
        Brow[q*4+0] = b4.x; Brow[q*4+1] = b4.y; Brow[q*4+2] = b4.z; Brow[q*4+3] = b4.w;
        Crow[q*4+0] = c4.x; Crow[q*4+1] = c4.y; Crow[q*4+2] = c4.z; Crow[q*4+3] = c4.w;
    }
    float bc = 0.f, cb = 0.f;
    #pragma unroll
    for (int a = 0; a < 16; ++a) {
        bc += Brow[a] * CtC[a * RK + r];
        cb += Crow[a] * BtB[a * RK + r];
    }
    const float Ddv = Dd[d];
    const float invN = 1.0f / (float)NROWS;   // fp32(16384 + 1e-8) == 16384
    const float gradB = -G1[idx] * invN + L2c * (SCALEc * bc + Ddv * Crow[r]);
    const float gradC = -G2[idx] * invN + L2c * (SCALEc * cb + Ddv * Brow[r]);
    const float sB = MOMc * S_B[idx] - LRc * gradB;
    const float sC = MOMc * S_C[idx] - LRc * gradC;
    outSB[idx] = sB;
    outSC[idx] = sC;
    outB[idx] = (1.0f - alpha) * B[idx] + sB;
    outC[idx] = (1.0f - alpha) * C[idx] + sC;
}

// ---------------------------------------------------------------------------
extern "C" void kernel_launch(void* const* d_in, const int* in_sizes, int n_in,
                              void* d_out, int out_size, void* d_ws, size_t ws_size,
                              hipStream_t stream)
{
    const float* k   = (const float*)d_in[0];
    const float* v   = (const float*)d_in[1];
    const float* B   = (const float*)d_in[2];
    const float* C   = (const float*)d_in[3];
    const float* Dd  = (const float*)d_in[4];
    const float* S_B = (const float*)d_in[5];
    const float* S_C = (const float*)d_in[6];
    const float* gam = (const float*)d_in[7];
    const float* bet = (const float*)d_in[8];
    const float* W1  = (const float*)d_in[9];
    const float* b1  = (const float*)d_in[10];
    const float* W2  = (const float*)d_in[11];
    const float* b2  = (const float*)d_in[12];

    float* out      = (float*)d_out;
    float* ro       = out;                                  // [N, D]
    float* outB     = out + (size_t)NROWS * DM;             // [D, R]
    float* outC     = outB + (size_t)DM * RK;
    float* outSB    = outC + (size_t)DM * RK;
    float* outSC    = outSB + (size_t)DM * RK;
    float* outAlpha = outSC + (size_t)DM * RK;              // scalar

    float* ws     = (float*)d_ws;
    float* kC_g   = ws;                                     // N*R   (1 MB)
    float* colsum = kC_g + (size_t)NROWS * RK;              // D
    float* G1     = colsum + DM;                            // D*R
    float* G2     = G1 + (size_t)DM * RK;                   // D*R
    float* CtC    = G2 + (size_t)DM * RK;                   // 256
    float* BtB    = CtC + 256;                              // 256
    float* h1     = BtB + 256;                              // D
    float* h2     = h1 + DM;                                // D
    float* alphaW = h2 + DM;                                // 1

    // zero accumulators: colsum, G1, G2, CtC, BtB (contiguous)
    hipMemsetAsync(colsum, 0, (size_t)(DM + 2 * DM * RK + 512) * sizeof(float), stream);

    hipLaunchKernelGGL(k_ctc, dim3(16), dim3(256), 0, stream, B, C, BtB, CtC);
    hipLaunchKernelGGL(k_A, dim3(256), dim3(512), 0, stream,
                       k, v, B, C, Dd, BtB, kC_g, G2, colsum);
    hipLaunchKernelGGL(k_B, dim3(512), dim3(256), 0, stream,
                       k, v, B, Dd, kC_g, ro, G1);
    hipLaunchKernelGGL(k_ln, dim3(1), dim3(256), 0, stream, colsum, gam, bet, h1);
    hipLaunchKernelGGL(k_gemv, dim3(512), dim3(256), 0, stream, h1, W1, b1, h2);
    hipLaunchKernelGGL(k_alpha, dim3(1), dim3(256), 0, stream, h2, W2, b2, alphaW, outAlpha);
    hipLaunchKernelGGL(k_update, dim3(128), dim3(256), 0, stream,
                       B, C, Dd, S_B, S_C, G1, G2, CtC, BtB, alphaW,
                       outB, outC, outSB, outSC);
}

// Round 3
// 1075.872 us; speedup vs baseline: 1.0836x; 1.0836x over previous
//
#include <hip/hip_runtime.h>
#include <math.h>

#define NROWS 16384
#define DM    2048
#define RK    16
#define LRc    1e-3f
#define L2c    1e-4f
#define MOMc   0.9f
#define SCALEc 0.1f
#define LNEPS  1e-5f

typedef __attribute__((ext_vector_type(8))) short short8;
typedef __attribute__((ext_vector_type(4))) float floatx4;

union U4S8 { uint4 u4; short8 s8; unsigned u[4]; };

__device__ inline unsigned f2bf1(float x) {
    unsigned u = __builtin_bit_cast(unsigned, x);
    return (u + 0x7fffu + ((u >> 16) & 1u)) >> 16;   // RNE bf16 bits
}
__device__ inline unsigned pk2(float lo, float hi) {
    return f2bf1(lo) | (f2bf1(hi) << 16);
}

// ---------------------------------------------------------------------------
// k_prep: blocks 0-15: BtB/CtC (atomic). blocks 16-31: pack B,C,D∘B into
// MFMA B-operand fragment layout (lane l, word q: bf16 pair for
// k = 8*(l>>4) + 2q {+1}, col = l&15, per 32-d chunk c).  block 32: D flag.
// ---------------------------------------------------------------------------
__global__ __launch_bounds__(256) void k_prep(
    const float* __restrict__ B, const float* __restrict__ C,
    const float* __restrict__ Dd,
    float* __restrict__ BtB, float* __restrict__ CtC,
    uint4* __restrict__ Cpk, uint4* __restrict__ Bpk, uint4* __restrict__ DBpk,
    int* __restrict__ flag)
{
    const int bid = blockIdx.x, t = threadIdx.x;
    if (bid < 16) {
        const int a = t >> 4, b = t & 15;
        const int dBeg = bid * 128;
        float sc = 0.f, sb = 0.f;
        for (int d = dBeg; d < dBeg + 128; ++d) {
            sc += C[d * RK + a] * C[d * RK + b];
            sb += B[d * RK + a] * B[d * RK + b];
        }
        atomicAdd(CtC + a * RK + b, sc);
        atomicAdd(BtB + a * RK + b, sb);
    } else if (bid < 32) {
        const int idx = (bid - 16) * 256 + t;      // 4096 = 64 chunks x 64 lanes
        const int c = idx >> 6, l = idx & 63;
        const int dbase = c * 32 + (l >> 4) * 8;
        const int col = l & 15;
        U4S8 uc, ub, ud;
        #pragma unroll
        for (int q = 0; q < 4; ++q) {
            const int d0 = dbase + 2 * q, d1 = d0 + 1;
            uc.u[q] = pk2(C[d0 * RK + col], C[d1 * RK + col]);
            ub.u[q] = pk2(B[d0 * RK + col], B[d1 * RK + col]);
            ud.u[q] = pk2(Dd[d0] * B[d0 * RK + col], Dd[d1] * B[d1 * RK + col]);
        }
        Cpk[idx] = uc.u4; Bpk[idx] = ub.u4; DBpk[idx] = ud.u4;
    } else {
        __shared__ int sh;
        if (t == 0) sh = 0;
        __syncthreads();
        int any = 0;
        for (int i = t; i < DM; i += 256) any |= (Dd[i] != 0.f) ? 1 : 0;
        if (any) sh = 1;
        __syncthreads();
        if (t == 0) *flag = sh;
    }
}

// ---------------------------------------------------------------------------
// k_A: MFMA pass. Block = 16 rows, 2 waves split the d-range (K-split).
//   kC = k@C, vB = v@B, kDB = (k o D)@B  -- all via mfma_f32_16x16x32_bf16.
// A-frag: lane l holds k[R0 + (l&15)][c*32 + (l>>4)*8 + e], e=0..7.
// acc:    lane l holds out[R0 + (l>>4)*4 + j][r = l&15].
// ---------------------------------------------------------------------------
__global__ __launch_bounds__(128) void k_A(
    const float* __restrict__ k, const float* __restrict__ v,
    const uint4* __restrict__ Cpk, const uint4* __restrict__ Bpk,
    const uint4* __restrict__ DBpk,
    float* __restrict__ kC_g, float* __restrict__ vB_g, float* __restrict__ kDB_g)
{
    __shared__ float4 red[3][64];
    const int t = threadIdx.x;
    const int lane = t & 63;
    const int w = t >> 6;
    const int R0 = blockIdx.x * 16;
    const int m = lane & 15;
    const int g = lane >> 4;
    const float* kp = k + (size_t)(R0 + m) * DM + g * 8;
    const float* vp = v + (size_t)(R0 + m) * DM + g * 8;

    floatx4 a0 = {0.f, 0.f, 0.f, 0.f};
    floatx4 a1 = {0.f, 0.f, 0.f, 0.f};
    floatx4 a2 = {0.f, 0.f, 0.f, 0.f};

    const int c0 = w * 32, c1 = c0 + 32;

    float4 ka = *(const float4*)(kp + c0 * 32);
    float4 kb = *(const float4*)(kp + c0 * 32 + 4);
    float4 va = *(const float4*)(vp + c0 * 32);
    float4 vb = *(const float4*)(vp + c0 * 32 + 4);
    uint4 cf = Cpk[c0 * 64 + lane];
    uint4 bf = Bpk[c0 * 64 + lane];
    uint4 df = DBpk[c0 * 64 + lane];

    for (int c = c0; c < c1; ++c) {
        const float4 kac = ka, kbc = kb, vac = va, vbc = vb;
        const uint4 cfc = cf, bfc = bf, dfc = df;
        const int cn = (c + 1 < c1) ? c + 1 : c;
        ka = *(const float4*)(kp + cn * 32);
        kb = *(const float4*)(kp + cn * 32 + 4);
        va = *(const float4*)(vp + cn * 32);
        vb = *(const float4*)(vp + cn * 32 + 4);
        cf = Cpk[cn * 64 + lane];
        bf = Bpk[cn * 64 + lane];
        df = DBpk[cn * 64 + lane];

        U4S8 kf, vf, cc, bb, dd;
        kf.u[0] = pk2(kac.x, kac.y); kf.u[1] = pk2(kac.z, kac.w);
        kf.u[2] = pk2(kbc.x, kbc.y); kf.u[3] = pk2(kbc.z, kbc.w);
        vf.u[0] = pk2(vac.x, vac.y); vf.u[1] = pk2(vac.z, vac.w);
        vf.u[2] = pk2(vbc.x, vbc.y); vf.u[3] = pk2(vbc.z, vbc.w);
        cc.u4 = cfc; bb.u4 = bfc; dd.u4 = dfc;

        a0 = __builtin_amdgcn_mfma_f32_16x16x32_bf16(kf.s8, cc.s8, a0, 0, 0, 0);
        a1 = __builtin_amdgcn_mfma_f32_16x16x32_bf16(vf.s8, bb.s8, a1, 0, 0, 0);
        a2 = __builtin_amdgcn_mfma_f32_16x16x32_bf16(kf.s8, dd.s8, a2, 0, 0, 0);
    }

    if (w == 1) {
        red[0][lane] = make_float4(a0[0], a0[1], a0[2], a0[3]);
        red[1][lane] = make_float4(a1[0], a1[1], a1[2], a1[3]);
        red[2][lane] = make_float4(a2[0], a2[1], a2[2], a2[3]);
    }
    __syncthreads();
    if (w == 0) {
        const float4 r0 = red[0][lane];
        const float4 r1 = red[1][lane];
        const float4 r2 = red[2][lane];
        const float s0[4] = {a0[0] + r0.x, a0[1] + r0.y, a0[2] + r0.z, a0[3] + r0.w};
        const float s1[4] = {a1[0] + r1.x, a1[1] + r1.y, a1[2] + r1.z, a1[3] + r1.w};
        const float s2[4] = {a2[0] + r2.x, a2[1] + r2.y, a2[2] + r2.z, a2[3] + r2.w};
        #pragma unroll
        for (int j = 0; j < 4; ++j) {
            const size_t o = (size_t)(R0 + g * 4 + j) * RK + m;
            kC_g[o]  = s0[j];
            vB_g[o]  = s1[j];
            kDB_g[o] = s2[j];
        }
    }
}

// ---------------------------------------------------------------------------
// k_mid: blocks 0-63: errB[n,:] = vB - kDB - 0.1*kC@BtB (in-place over kDB).
//        blocks 64-79: S2 = kC^T @ kC (16x16, atomic).
// ---------------------------------------------------------------------------
__global__ __launch_bounds__(256) void k_mid(
    const float* __restrict__ kC_g, const float* __restrict__ vB_g,
    float* __restrict__ eB_g, const float* __restrict__ BtB,
    float* __restrict__ S2)
{
    const int bid = blockIdx.x, t = threadIdx.x;
    if (bid < 64) {
        __shared__ float Bsh[256];
        Bsh[t] = BtB[t];
        __syncthreads();
        const int n = bid * 256 + t;
        float kc[16], vb[16], kdb[16];
        #pragma unroll
        for (int q = 0; q < 4; ++q) {
            const float4 a = *(const float4*)(kC_g + (size_t)n * RK + q * 4);
            const float4 b = *(const float4*)(vB_g + (size_t)n * RK + q * 4);
            const float4 c = *(const float4*)(eB_g + (size_t)n * RK + q * 4);
            kc[q*4+0]=a.x; kc[q*4+1]=a.y; kc[q*4+2]=a.z; kc[q*4+3]=a.w;
            vb[q*4+0]=b.x; vb[q*4+1]=b.y; vb[q*4+2]=b.z; vb[q*4+3]=b.w;
            kdb[q*4+0]=c.x; kdb[q*4+1]=c.y; kdb[q*4+2]=c.z; kdb[q*4+3]=c.w;
        }
        float out[16];
        #pragma unroll
        for (int r = 0; r < 16; ++r) {
            float acc = 0.f;
            #pragma unroll
            for (int s = 0; s < 16; ++s) acc += kc[s] * Bsh[s * 16 + r];
            out[r] = vb[r] - kdb[r] - SCALEc * acc;
        }
        #pragma unroll
        for (int q = 0; q < 4; ++q)
            *(float4*)(eB_g + (size_t)n * RK + q * 4) =
                make_float4(out[q*4+0], out[q*4+1], out[q*4+2], out[q*4+3]);
    } else {
        const int a = t >> 4, b = t & 15;
        const int n0 = (bid - 64) * 1024;
        float s = 0.f;
        for (int i = 0; i < 1024; ++i)
            s += kC_g[(size_t)(n0 + i) * RK + a] * kC_g[(size_t)(n0 + i) * RK + b];
        atomicAdd(S2 + a * RK + b, s);
    }
}

// ---------------------------------------------------------------------------
// k_B1: streams v once. ro[n,d] = 0.1*kC.B[d,:] (+ k*D if flag), err-free
// P1[d,r] += v[n,d]*kC[n,r] in registers, atomic flush.
// 512 blocks (2 d-slabs x 256 chunks of 64 rows), 256 thr, thread owns 4 d.
// ---------------------------------------------------------------------------
__global__ __launch_bounds__(256) void k_B1(
    const float* __restrict__ k, const float* __restrict__ v,
    const float* __restrict__ B, const float* __restrict__ Dd,
    const float* __restrict__ kC_g, const int* __restrict__ flag,
    float* __restrict__ ro, float* __restrict__ P1)
{
    __shared__ float kCch[64 * 16];
    const int t = threadIdx.x;
    const int slab = blockIdx.x & 1;
    const int chunk = blockIdx.x >> 1;
    const int d0 = slab * 1024 + t * 4;
    const int row0 = chunk * 64;
    const int dnz = *flag;

    float Breg[4][16], Dreg[4];
    #pragma unroll
    for (int i = 0; i < 4; ++i) {
        #pragma unroll
        for (int q = 0; q < 4; ++q) {
            const float4 b4 = *(const float4*)(B + (size_t)(d0 + i) * RK + q * 4);
            Breg[i][q*4+0] = b4.x; Breg[i][q*4+1] = b4.y;
            Breg[i][q*4+2] = b4.z; Breg[i][q*4+3] = b4.w;
        }
        Dreg[i] = Dd[d0 + i];
    }
    *(float4*)&kCch[t * 4] = *(const float4*)(kC_g + (size_t)row0 * RK + t * 4);
    __syncthreads();

    float p1[4][16];
    #pragma unroll
    for (int i = 0; i < 4; ++i)
        #pragma unroll
        for (int r = 0; r < 16; ++r) p1[i][r] = 0.f;

    float4 v0 = *(const float4*)(v + (size_t)row0 * DM + d0);
    float4 v1 = *(const float4*)(v + (size_t)(row0 + 1) * DM + d0);
    float4 k0 = make_float4(0.f, 0.f, 0.f, 0.f), k1 = k0;
    if (dnz) {
        k0 = *(const float4*)(k + (size_t)row0 * DM + d0);
        k1 = *(const float4*)(k + (size_t)(row0 + 1) * DM + d0);
    }

    for (int rr = 0; rr < 64; ++rr) {
        const int n = row0 + rr;
        const float4 vc = v0;
        const float4 kc4 = k0;
        const int np = row0 + ((rr + 2 < 64) ? rr + 2 : 63);
        v0 = v1; v1 = *(const float4*)(v + (size_t)np * DM + d0);
        if (dnz) { k0 = k1; k1 = *(const float4*)(k + (size_t)np * DM + d0); }

        float kcr[16];
        #pragma unroll
        for (int q = 0; q < 4; ++q) {
            const float4 c4 = *(const float4*)&kCch[rr * 16 + q * 4];
            kcr[q*4+0] = c4.x; kcr[q*4+1] = c4.y; kcr[q*4+2] = c4.z; kcr[q*4+3] = c4.w;
        }

        float roa[4];
        const float ka4[4] = {kc4.x, kc4.y, kc4.z, kc4.w};
        #pragma unroll
        for (int i = 0; i < 4; ++i) {
            float s = 0.f;
            #pragma unroll
            for (int r = 0; r < 16; ++r) s += kcr[r] * Breg[i][r];
            roa[i] = SCALEc * s;
            if (dnz) roa[i] += ka4[i] * Dreg[i];
        }
        *(float4*)(ro + (size_t)n * DM + d0) = make_float4(roa[0], roa[1], roa[2], roa[3]);

        const float va4[4] = {vc.x, vc.y, vc.z, vc.w};
        #pragma unroll
        for (int r = 0; r < 16; ++r) {
            p1[0][r] += va4[0] * kcr[r];
            p1[1][r] += va4[1] * kcr[r];
            p1[2][r] += va4[2] * kcr[r];
            p1[3][r] += va4[3] * kcr[r];
        }
    }

    #pragma unroll
    for (int i = 0; i < 4; ++i)
        #pragma unroll
        for (int r = 0; r < 16; ++r)
            atomicAdd(P1 + (size_t)(d0 + i) * RK + r, p1[i][r]);
}

// ---------------------------------------------------------------------------
// k_G2 (runs when flag==0): streams k once. G2[d,r] += k[n,d]*errB[n,r],
// colsum[d] += k[n,d]. Same geometry as k_B1.
// ---------------------------------------------------------------------------
__global__ __launch_bounds__(256) void k_G2(
    const float* __restrict__ k, const float* __restrict__ eB_g,
    const int* __restrict__ flag,
    float* __restrict__ G2, float* __restrict__ colsum)
{
    if (*flag != 0) return;
    __shared__ float ebch[64 * 16];
    const int t = threadIdx.x;
    const int slab = blockIdx.x & 1;
    const int chunk = blockIdx.x >> 1;
    const int d0 = slab * 1024 + t * 4;
    const int row0 = chunk * 64;

    *(float4*)&ebch[t * 4] = *(const float4*)(eB_g + (size_t)row0 * RK + t * 4);
    __syncthreads();

    float g2[4][16];
    #pragma unroll
    for (int i = 0; i < 4; ++i)
        #pragma unroll
        for (int r = 0; r < 16; ++r) g2[i][r] = 0.f;
    float cs[4] = {0.f, 0.f, 0.f, 0.f};

    float4 k0 = *(const float4*)(k + (size_t)row0 * DM + d0);
    float4 k1 = *(const float4*)(k + (size_t)(row0 + 1) * DM + d0);

    for (int rr = 0; rr < 64; ++rr) {
        const float4 kc4 = k0;
        const int np = row0 + ((rr + 2 < 64) ? rr + 2 : 63);
        k0 = k1; k1 = *(const float4*)(k + (size_t)np * DM + d0);

        float eb[16];
        #pragma unroll
        for (int q = 0; q < 4; ++q) {
            const float4 e4 = *(const float4*)&ebch[rr * 16 + q * 4];
            eb[q*4+0] = e4.x; eb[q*4+1] = e4.y; eb[q*4+2] = e4.z; eb[q*4+3] = e4.w;
        }
        const float ka4[4] = {kc4.x, kc4.y, kc4.z, kc4.w};
        cs[0] += ka4[0]; cs[1] += ka4[1]; cs[2] += ka4[2]; cs[3] += ka4[3];
        #pragma unroll
        for (int r = 0; r < 16; ++r) {
            g2[0][r] += ka4[0] * eb[r];
            g2[1][r] += ka4[1] * eb[r];
            g2[2][r] += ka4[2] * eb[r];
            g2[3][r] += ka4[3] * eb[r];
        }
    }

    #pragma unroll
    for (int i = 0; i < 4; ++i) atomicAdd(colsum + d0 + i, cs[i]);
    #pragma unroll
    for (int i = 0; i < 4; ++i)
        #pragma unroll
        for (int r = 0; r < 16; ++r)
            atomicAdd(G2 + (size_t)(d0 + i) * RK + r, g2[i][r]);
}

// ---------------------------------------------------------------------------
// k_G2D (runs when flag!=0): G2 + colsum + Q = k^T@kC (needed for D-term).
// ---------------------------------------------------------------------------
__global__ __launch_bounds__(256) void k_G2D(
    const float* __restrict__ k, const float* __restrict__ eB_g,
    const float* __restrict__ kC_g, const int* __restrict__ flag,
    float* __restrict__ G2, float* __restrict__ colsum, float* __restrict__ Q)
{
    if (*flag == 0) return;
    __shared__ float ebch[64 * 16];
    __shared__ float kcch[64 * 16];
    const int t = threadIdx.x;
    const int slab = blockIdx.x & 1;
    const int chunk = blockIdx.x >> 1;
    const int d0 = slab * 1024 + t * 4;
    const int row0 = chunk * 64;

    *(float4*)&ebch[t * 4] = *(const float4*)(eB_g + (size_t)row0 * RK + t * 4);
    *(float4*)&kcch[t * 4] = *(const float4*)(kC_g + (size_t)row0 * RK + t * 4);
    __syncthreads();

    float g2[4][16], q2[4][16];
    #pragma unroll
    for (int i = 0; i < 4; ++i)
        #pragma unroll
        for (int r = 0; r < 16; ++r) { g2[i][r] = 0.f; q2[i][r] = 0.f; }
    float cs[4] = {0.f, 0.f, 0.f, 0.f};

    float4 k0 = *(const float4*)(k + (size_t)row0 * DM + d0);
    float4 k1 = *(const float4*)(k + (size_t)(row0 + 1) * DM + d0);

    for (int rr = 0; rr < 64; ++rr) {
        const float4 kc4 = k0;
        const int np = row0 + ((rr + 2 < 64) ? rr + 2 : 63);
        k0 = k1; k1 = *(const float4*)(k + (size_t)np * DM + d0);
        const float ka4[4] = {kc4.x, kc4.y, kc4.z, kc4.w};
        cs[0] += ka4[0]; cs[1] += ka4[1]; cs[2] += ka4[2]; cs[3] += ka4[3];
        #pragma unroll
        for (int r = 0; r < 16; ++r) {
            const float eb = ebch[rr * 16 + r];
            const float kc = kcch[rr * 16 + r];
            g2[0][r] += ka4[0] * eb;  q2[0][r] += ka4[0] * kc;
            g2[1][r] += ka4[1] * eb;  q2[1][r] += ka4[1] * kc;
            g2[2][r] += ka4[2] * eb;  q2[2][r] += ka4[2] * kc;
            g2[3][r] += ka4[3] * eb;  q2[3][r] += ka4[3] * kc;
        }
    }

    #pragma unroll
    for (int i = 0; i < 4; ++i) atomicAdd(colsum + d0 + i, cs[i]);
    #pragma unroll
    for (int i = 0; i < 4; ++i)
        #pragma unroll
        for (int r = 0; r < 16; ++r) {
            atomicAdd(G2 + (size_t)(d0 + i) * RK + r, g2[i][r]);
            atomicAdd(Q + (size_t)(d0 + i) * RK + r, q2[i][r]);
        }
}

// ---------------------------------------------------------------------------
// k_ln: k_mean = colsum/N; h1 = LayerNorm(k_mean)*gamma + beta.
// ---------------------------------------------------------------------------
__global__ __launch_bounds__(256) void k_ln(
    const float* __restrict__ colsum,
    const float* __restrict__ gam, const float* __restrict__ bet,
    float* __restrict__ h1)
{
    __shared__ float red[256];
    __shared__ float mu_sh, var_sh;
    const int t = threadIdx.x;
    float x[8];
    float s = 0.f;
    #pragma unroll
    for (int i = 0; i < 8; ++i) {
        x[i] = colsum[t + 256 * i] * (1.0f / (float)NROWS);
        s += x[i];
    }
    red[t] = s; __syncthreads();
    for (int off = 128; off > 0; off >>= 1) {
        if (t < off) red[t] += red[t + off];
        __syncthreads();
    }
    if (t == 0) mu_sh = red[0] * (1.0f / (float)DM);
    __syncthreads();
    const float mu = mu_sh;
    float s2 = 0.f;
    #pragma unroll
    for (int i = 0; i < 8; ++i) { const float dd = x[i] - mu; s2 += dd * dd; }
    __syncthreads();
    red[t] = s2; __syncthreads();
    for (int off = 128; off > 0; off >>= 1) {
        if (t < off) red[t] += red[t + off];
        __syncthreads();
    }
    if (t == 0) var_sh = red[0] * (1.0f / (float)DM);
    __syncthreads();
    const float rstd = rsqrtf(var_sh + LNEPS);
    #pragma unroll
    for (int i = 0; i < 8; ++i) {
        const int d = t + 256 * i;
        h1[d] = (x[i] - mu) * rstd * gam[d] + bet[d];
    }
}

// ---------------------------------------------------------------------------
// k_gemv: h2[i] = silu(h1 . W1[i,:] + b1[i]).
// ---------------------------------------------------------------------------
__global__ __launch_bounds__(256) void k_gemv(
    const float* __restrict__ h1, const float* __restrict__ W1,
    const float* __restrict__ b1, float* __restrict__ h2)
{
    const int t = threadIdx.x;
    const int lane = t & 63;
    const int w = t >> 6;
    const int row = blockIdx.x * 4 + w;
    const float* wr = W1 + (size_t)row * DM;
    float s = 0.f;
    #pragma unroll
    for (int j = 0; j < 8; ++j) {
        const float4 a = *(const float4*)(wr + j * 256 + lane * 4);
        const float4 b = *(const float4*)(h1 + j * 256 + lane * 4);
        s += a.x * b.x + a.y * b.y + a.z * b.z + a.w * b.w;
    }
    #pragma unroll
    for (int off = 32; off > 0; off >>= 1) s += __shfl_down(s, off);
    if (lane == 0) {
        const float val = s + b1[row];
        h2[row] = val / (1.0f + expf(-val));
    }
}

// ---------------------------------------------------------------------------
// k_alpha: alpha = sigmoid(h2 . W2 + b2).
// ---------------------------------------------------------------------------
__global__ __launch_bounds__(256) void k_alpha(
    const float* __restrict__ h2, const float* __restrict__ W2,
    const float* __restrict__ b2,
    float* __restrict__ alpha_ws, float* __restrict__ out_alpha)
{
    __shared__ float red[256];
    const int t = threadIdx.x;
    float s = 0.f;
    for (int i = t; i < DM; i += 256) s += h2[i] * W2[i];
    red[t] = s; __syncthreads();
    for (int off = 128; off > 0; off >>= 1) {
        if (t < off) red[t] += red[t + off];
        __syncthreads();
    }
    if (t == 0) {
        const float logit = red[0] + b2[0];
        const float a = 1.0f / (1.0f + expf(-logit));
        alpha_ws[0] = a;
        out_alpha[0] = a;
    }
}

// ---------------------------------------------------------------------------
// k_update: G1 = P1 - 0.1*B@S2 - D o Q; then grads, momentum, B/C update.
// ---------------------------------------------------------------------------
__global__ __launch_bounds__(256) void k_update(
    const float* __restrict__ B, const float* __restrict__ C,
    const float* __restrict__ Dd,
    const float* __restrict__ S_B, const float* __restrict__ S_C,
    const float* __restrict__ P1, const float* __restrict__ G2,
    const float* __restrict__ Q, const float* __restrict__ S2,
    const float* __restrict__ CtC, const float* __restrict__ BtB,
    const float* __restrict__ alpha_ws,
    float* __restrict__ outB, float* __restrict__ outC,
    float* __restrict__ outSB, float* __restrict__ outSC)
{
    const int idx = blockIdx.x * 256 + threadIdx.x;   // [0, 32768)
    const int d = idx >> 4, r = idx & 15;
    const float alpha = alpha_ws[0];

    float Brow[16], Crow[16];
    #pragma unroll
    for (int q = 0; q < 4; ++q) {
        const float4 b4 = *(const float4*)(B + (size_t)d * RK + q * 4);
        const float4 c4 = *(const float4*)(C + (size_t)d * RK + q * 4);
        Brow[q*4+0] = b4.x; Brow[q*4+1] = b4.y; Brow[q*4+2] = b4.z; Brow[q*4+3] = b4.w;
        Crow[q*4+0] = c4.x; Crow[q*4+1] = c4.y; Crow[q*4+2] = c4.z; Crow[q*4+3] = c4.w;
    }
    float bc = 0.f, cb = 0.f, bs2 = 0.f;
    #pragma unroll
    for (int a = 0; a < 16; ++a) {
        bc  += Brow[a] * CtC[a * RK + r];
        cb  += Crow[a] * BtB[a * RK + r];
        bs2 += Brow[a] * S2[a * RK + r];
    }
    const float Ddv = Dd[d];
    const float invN = 1.0f / (float)NROWS;
    const float G1v = P1[idx] - SCALEc * bs2 - Ddv * Q[idx];
    const float gradB = -G1v * invN + L2c * (SCALEc * bc + Ddv * Crow[r]);
    const float gradC = -G2[idx] * invN + L2c * (SCALEc * cb + Ddv * Brow[r]);
    const float sB = MOMc * S_B[idx] - LRc * gradB;
    const float sC = MOMc * S_C[idx] - LRc * gradC;
    outSB[idx] = sB;
    outSC[idx] = sC;
    outB[idx] = (1.0f - alpha) * B[idx] + sB;
    outC[idx] = (1.0f - alpha) * C[idx] + sC;
}

// ---------------------------------------------------------------------------
extern "C" void kernel_launch(void* const* d_in, const int* in_sizes, int n_in,
                              void* d_out, int out_size, void* d_ws, size_t ws_size,
                              hipStream_t stream)
{
    const float* k   = (const float*)d_in[0];
    const float* v   = (const float*)d_in[1];
    const float* B   = (const float*)d_in[2];
    const float* C   = (const float*)d_in[3];
    const float* Dd  = (const float*)d_in[4];
    const float* S_B = (const float*)d_in[5];
    const float* S_C = (const float*)d_in[6];
    const float* gam = (const float*)d_in[7];
    const float* bet = (const float*)d_in[8];
    const float* W1  = (const float*)d_in[9];
    const float* b1  = (const float*)d_in[10];
    const float* W2  = (const float*)d_in[11];
    const float* b2  = (const float*)d_in[12];

    float* out      = (float*)d_out;
    float* ro       = out;                                  // [N, D]
    float* outB     = out + (size_t)NROWS * DM;
    float* outC     = outB + (size_t)DM * RK;
    float* outSB    = outC + (size_t)DM * RK;
    float* outSC    = outSB + (size_t)DM * RK;
    float* outAlpha = outSC + (size_t)DM * RK;

    float* ws = (float*)d_ws;
    float* kC_g   = ws;                                     // N*16
    float* vB_g   = kC_g + (size_t)NROWS * RK;              // N*16
    float* eB_g   = vB_g + (size_t)NROWS * RK;              // N*16 (kDB -> errB)
    float* P1     = eB_g + (size_t)NROWS * RK;              // 32768 --- zero region start
    float* G2     = P1 + (size_t)DM * RK;                   // 32768
    float* Q      = G2 + (size_t)DM * RK;                   // 32768
    float* S2     = Q + (size_t)DM * RK;                    // 256
    float* CtC    = S2 + 256;                               // 256
    float* BtB    = CtC + 256;                              // 256
    float* colsum = BtB + 256;                              // 2048 --- zero region end
    float* h1     = colsum + DM;                            // 2048
    float* h2     = h1 + DM;                                // 2048
    uint4* Cpk    = (uint4*)(h2 + DM);                      // 4096 uint4
    uint4* Bpk    = Cpk + 4096;
    uint4* DBpk   = Bpk + 4096;
    float* alphaW = (float*)(DBpk + 4096);                  // 1
    int*   flag   = (int*)(alphaW + 1);                     // 1

    // zero P1..colsum: 3*32768 + 3*256 + 2048 = 101120 floats
    hipMemsetAsync(P1, 0, (size_t)101120 * sizeof(float), stream);

    hipLaunchKernelGGL(k_prep, dim3(33), dim3(256), 0, stream,
                       B, C, Dd, BtB, CtC, Cpk, Bpk, DBpk, flag);
    hipLaunchKernelGGL(k_A, dim3(1024), dim3(128), 0, stream,
                       k, v, Cpk, Bpk, DBpk, kC_g, vB_g, eB_g);
    hipLaunchKernelGGL(k_mid, dim3(80), dim3(256), 0, stream,
                       kC_g, vB_g, eB_g, BtB, S2);
    hipLaunchKernelGGL(k_B1, dim3(512), dim3(256), 0, stream,
                       k, v, B, Dd, kC_g, flag, ro, P1);
    hipLaunchKernelGGL(k_G2, dim3(512), dim3(256), 0, stream,
                       k, eB_g, flag, G2, colsum);
    hipLaunchKernelGGL(k_G2D, dim3(512), dim3(256), 0, stream,
                       k, eB_g, kC_g, flag, G2, colsum, Q);
    hipLaunchKernelGGL(k_ln, dim3(1), dim3(256), 0, stream, colsum, gam, bet, h1);
    hipLaunchKernelGGL(k_gemv, dim3(512), dim3(256), 0, stream, h1, W1, b1, h2);
    hipLaunchKernelGGL(k_alpha, dim3(1), dim3(256), 0, stream, h2, W2, b2, alphaW, outAlpha);
    hipLaunchKernelGGL(k_update, dim3(128), dim3(256), 0, stream,
                       B, C, Dd, S_B, S_C, P1, G2, Q, S2, CtC, BtB, alphaW,
                       outB, outC, outSB, outSC);
}

// Round 4
// 214.631 us; speedup vs baseline: 5.4315x; 5.0127x over previous
//
#include <hip/hip_runtime.h>
#include <hip/hip_bf16.h>
#include <math.h>

#define NROWS 16384
#define DM    2048
#define RK    16
#define LRc    1e-3f
#define L2c    1e-4f
#define MOMc   0.9f
#define SCALEc 0.1f
#define LNEPS  1e-5f

typedef __attribute__((ext_vector_type(8))) short short8;
typedef __attribute__((ext_vector_type(4))) float floatx4;

union U4S8 { uint4 u4; short8 s8; unsigned u[4]; };

__device__ inline unsigned pk2(float lo, float hi) {
    union { __hip_bfloat162 h; unsigned u; } cv;
    cv.h = __float22bfloat162_rn(make_float2(lo, hi));
    return cv.u;
}

// hi/lo bf16 split of a float pair (ho = bf16(x), lo = bf16(x - hi))
#define SPLIT_PAIR(x0, x1, ho, lo_) {                                      \
    const unsigned hh_ = pk2((x0), (x1));                                  \
    const float hx0_ = __builtin_bit_cast(float, (hh_ & 0xffffu) << 16);   \
    const float hx1_ = __builtin_bit_cast(float, hh_ & 0xffff0000u);       \
    (ho) = hh_; (lo_) = pk2((x0) - hx0_, (x1) - hx1_); }

// ---------------------------------------------------------------------------
// k_prep: blocks 0-15: BtB/CtC (atomic). blocks 16-31: pack B,C,D∘B into
// MFMA B-operand fragment layout (lane l: col=l&15, k-rows 8*(l>>4)+2q{,+1},
// per 32-d chunk). block 32: D!=0 flag.
// ---------------------------------------------------------------------------
__global__ __launch_bounds__(256) void k_prep(
    const float* __restrict__ B, const float* __restrict__ C,
    const float* __restrict__ Dd,
    float* __restrict__ BtB, float* __restrict__ CtC,
    uint4* __restrict__ Cpk, uint4* __restrict__ Bpk, uint4* __restrict__ DBpk,
    int* __restrict__ flag)
{
    const int bid = blockIdx.x, t = threadIdx.x;
    if (bid < 16) {
        const int a = t >> 4, b = t & 15;
        const int dBeg = bid * 128;
        float sc = 0.f, sb = 0.f;
        for (int d = dBeg; d < dBeg + 128; ++d) {
            sc += C[d * RK + a] * C[d * RK + b];
            sb += B[d * RK + a] * B[d * RK + b];
        }
        atomicAdd(CtC + a * RK + b, sc);
        atomicAdd(BtB + a * RK + b, sb);
    } else if (bid < 32) {
        const int idx = (bid - 16) * 256 + t;      // 4096 = 64 chunks x 64 lanes
        const int c = idx >> 6, l = idx & 63;
        const int dbase = c * 32 + (l >> 4) * 8;
        const int col = l & 15;
        U4S8 uc, ub, ud;
        #pragma unroll
        for (int q = 0; q < 4; ++q) {
            const int d0 = dbase + 2 * q, d1 = d0 + 1;
            uc.u[q] = pk2(C[d0 * RK + col], C[d1 * RK + col]);
            ub.u[q] = pk2(B[d0 * RK + col], B[d1 * RK + col]);
            ud.u[q] = pk2(Dd[d0] * B[d0 * RK + col], Dd[d1] * B[d1 * RK + col]);
        }
        Cpk[idx] = uc.u4; Bpk[idx] = ub.u4; DBpk[idx] = ud.u4;
    } else {
        __shared__ int sh;
        if (t == 0) sh = 0;
        __syncthreads();
        int any = 0;
        for (int i = t; i < DM; i += 256) any |= (Dd[i] != 0.f) ? 1 : 0;
        if (any) sh = 1;
        __syncthreads();
        if (t == 0) *flag = sh;
    }
}

// ---------------------------------------------------------------------------
// k_A: MFMA row-reductions. Block = 16 rows x 4 waves (K-split over d).
//   kC = k@C, vB = v@B, kDB = (k o D)@B (skipped when D==0).
// A-frag: lane l holds x[R0+(l&15)][c*32 + (l>>4)*8 + e], e=0..7.
// acc:    lane l, reg j -> out[R0 + (l>>4)*4 + j][r=l&15].
// 1024 blocks x 256 threads -> 4096 waves (4/SIMD).
// ---------------------------------------------------------------------------
__global__ __launch_bounds__(256) void k_A(
    const float* __restrict__ k, const float* __restrict__ v,
    const uint4* __restrict__ Cpk, const uint4* __restrict__ Bpk,
    const uint4* __restrict__ DBpk, const int* __restrict__ flag,
    float* __restrict__ kC_g, float* __restrict__ vB_g, float* __restrict__ kDB_g)
{
    __shared__ floatx4 red[3][4][64];
    const int t = threadIdx.x;
    const int lane = t & 63;
    const int w = t >> 6;
    const int R0 = blockIdx.x * 16;
    const int m = lane & 15;
    const int g = lane >> 4;
    const int dnz = *flag;
    const float* kp = k + (size_t)(R0 + m) * DM + g * 8;
    const float* vp = v + (size_t)(R0 + m) * DM + g * 8;

    floatx4 a0 = {0.f,0.f,0.f,0.f}, a1 = {0.f,0.f,0.f,0.f}, a2 = {0.f,0.f,0.f,0.f};
    const int c0 = w * 16;

    float4 ka = *(const float4*)(kp + c0 * 32);
    float4 kb = *(const float4*)(kp + c0 * 32 + 4);
    float4 va = *(const float4*)(vp + c0 * 32);
    float4 vb = *(const float4*)(vp + c0 * 32 + 4);
    uint4 cf = Cpk[c0 * 64 + lane];
    uint4 bf = Bpk[c0 * 64 + lane];
    uint4 df = make_uint4(0u,0u,0u,0u);
    if (dnz) df = DBpk[c0 * 64 + lane];

    for (int cc = 0; cc < 16; ++cc) {
        const int c = c0 + cc;
        const float4 kac = ka, kbc = kb, vac = va, vbc = vb;
        const uint4 cfc = cf, bfc = bf, dfc = df;
        const int cn = (cc + 1 < 16) ? c + 1 : c;
        ka = *(const float4*)(kp + cn * 32);
        kb = *(const float4*)(kp + cn * 32 + 4);
        va = *(const float4*)(vp + cn * 32);
        vb = *(const float4*)(vp + cn * 32 + 4);
        cf = Cpk[cn * 64 + lane];
        bf = Bpk[cn * 64 + lane];
        if (dnz) df = DBpk[cn * 64 + lane];

        U4S8 kf, vf, cu, bu, du;
        kf.u[0] = pk2(kac.x, kac.y); kf.u[1] = pk2(kac.z, kac.w);
        kf.u[2] = pk2(kbc.x, kbc.y); kf.u[3] = pk2(kbc.z, kbc.w);
        vf.u[0] = pk2(vac.x, vac.y); vf.u[1] = pk2(vac.z, vac.w);
        vf.u[2] = pk2(vbc.x, vbc.y); vf.u[3] = pk2(vbc.z, vbc.w);
        cu.u4 = cfc; bu.u4 = bfc; du.u4 = dfc;

        a0 = __builtin_amdgcn_mfma_f32_16x16x32_bf16(kf.s8, cu.s8, a0, 0, 0, 0);
        a1 = __builtin_amdgcn_mfma_f32_16x16x32_bf16(vf.s8, bu.s8, a1, 0, 0, 0);
        if (dnz)
            a2 = __builtin_amdgcn_mfma_f32_16x16x32_bf16(kf.s8, du.s8, a2, 0, 0, 0);
    }

    red[0][w][lane] = a0;
    red[1][w][lane] = a1;
    red[2][w][lane] = a2;
    __syncthreads();
    if (w == 0) {
        const floatx4 s0 = red[0][0][lane] + red[0][1][lane] + red[0][2][lane] + red[0][3][lane];
        const floatx4 s1 = red[1][0][lane] + red[1][1][lane] + red[1][2][lane] + red[1][3][lane];
        const floatx4 s2 = red[2][0][lane] + red[2][1][lane] + red[2][2][lane] + red[2][3][lane];
        #pragma unroll
        for (int j = 0; j < 4; ++j) {
            const size_t o = (size_t)(R0 + g * 4 + j) * RK + m;
            kC_g[o] = s0[j];
            vB_g[o] = s1[j];
            if (dnz) kDB_g[o] = s2[j];
        }
    }
}

// ---------------------------------------------------------------------------
// k_mid: errB[n,:] = vB - kDB - 0.1*kC@BtB (into eB_g). 64 blocks x 256.
// ---------------------------------------------------------------------------
__global__ __launch_bounds__(256) void k_mid(
    const float* __restrict__ kC_g, const float* __restrict__ vB_g,
    float* __restrict__ eB_g, const float* __restrict__ BtB,
    const int* __restrict__ flag)
{
    __shared__ float Bsh[256];
    const int t = threadIdx.x;
    Bsh[t] = BtB[t];
    __syncthreads();
    const int dnz = *flag;
    const int n = blockIdx.x * 256 + t;
    float kc[16], vb[16], kdb[16];
    #pragma unroll
    for (int q = 0; q < 4; ++q) {
        const float4 a = *(const float4*)(kC_g + (size_t)n * RK + q * 4);
        const float4 b = *(const float4*)(vB_g + (size_t)n * RK + q * 4);
        kc[q*4+0]=a.x; kc[q*4+1]=a.y; kc[q*4+2]=a.z; kc[q*4+3]=a.w;
        vb[q*4+0]=b.x; vb[q*4+1]=b.y; vb[q*4+2]=b.z; vb[q*4+3]=b.w;
        kdb[q*4+0]=0.f; kdb[q*4+1]=0.f; kdb[q*4+2]=0.f; kdb[q*4+3]=0.f;
    }
    if (dnz) {
        #pragma unroll
        for (int q = 0; q < 4; ++q) {
            const float4 c = *(const float4*)(eB_g + (size_t)n * RK + q * 4);
            kdb[q*4+0]=c.x; kdb[q*4+1]=c.y; kdb[q*4+2]=c.z; kdb[q*4+3]=c.w;
        }
    }
    float out[16];
    #pragma unroll
    for (int r = 0; r < 16; ++r) {
        float acc = 0.f;
        #pragma unroll
        for (int s = 0; s < 16; ++s) acc += kc[s] * Bsh[s * 16 + r];
        out[r] = vb[r] - kdb[r] - SCALEc * acc;
    }
    #pragma unroll
    for (int q = 0; q < 4; ++q)
        *(float4*)(eB_g + (size_t)n * RK + q * 4) =
            make_float4(out[q*4+0], out[q*4+1], out[q*4+2], out[q*4+3]);
}

// ---------------------------------------------------------------------------
// k_pack: pack kC^T and errB^T into MFMA A-operand fragments, hi/lo split.
// chunk c (32 rows), lane l: A[row=l&15][kk=(l>>4)*8+e] = X[c*32+kk][l&15].
// 128 blocks x 256 (32768 threads = 512 chunks x 64 lanes).
// ---------------------------------------------------------------------------
__global__ __launch_bounds__(256) void k_pack(
    const float* __restrict__ kC_g, const float* __restrict__ eB_g,
    uint4* __restrict__ kCh, uint4* __restrict__ kCl,
    uint4* __restrict__ eBh, uint4* __restrict__ eBl)
{
    const int idx = blockIdx.x * 256 + threadIdx.x;   // 0..32767
    const int c = idx >> 6, l = idx & 63;
    const int col = l & 15;
    const int nb = c * 32 + (l >> 4) * 8;
    U4S8 ah, al, bh, bl;
    #pragma unroll
    for (int q = 0; q < 4; ++q) {
        const int n0 = nb + 2 * q;
        const float x0 = kC_g[(size_t)n0 * RK + col];
        const float x1 = kC_g[(size_t)(n0 + 1) * RK + col];
        const float y0 = eB_g[(size_t)n0 * RK + col];
        const float y1 = eB_g[(size_t)(n0 + 1) * RK + col];
        SPLIT_PAIR(x0, x1, ah.u[q], al.u[q]);
        SPLIT_PAIR(y0, y1, bh.u[q], bl.u[q]);
    }
    kCh[idx] = ah.u4; kCl[idx] = al.u4;
    eBh[idx] = bh.u4; eBl[idx] = bl.u4;
}

// ---------------------------------------------------------------------------
// k_T: all tall reductions via MFMA.
//   P1^T = kC^T @ v (hi/lo split, 3 mfma), G2^T = errB^T @ k (split, 3 mfma),
//   Q^T = kC^T @ k (1), S2 = kC^T @ kC (1, flushed by dgrp==0 only),
//   colsum[d] = sum_n k[n,d] (shfl reduce + atomic).
// grid = 32 d-groups x 32 row-chunks = 1024 blocks x 256 thr (4 waves).
// wave owns 16 d-cols; 16 iters x 32 rows.
// ---------------------------------------------------------------------------
__global__ __launch_bounds__(256) void k_T(
    const float* __restrict__ k, const float* __restrict__ v,
    const uint4* __restrict__ kCh, const uint4* __restrict__ kCl,
    const uint4* __restrict__ eBh, const uint4* __restrict__ eBl,
    float* __restrict__ P1, float* __restrict__ G2, float* __restrict__ Q,
    float* __restrict__ S2, float* __restrict__ colsum)
{
    const int t = threadIdx.x;
    const int lane = t & 63;
    const int w = t >> 6;
    const int dgrp = blockIdx.x & 31;
    const int chunk = blockIdx.x >> 5;
    const int d = dgrp * 64 + w * 16 + (lane & 15);
    const int rowoff = (lane >> 4) * 8;
    const int c0 = chunk * 16;

    floatx4 accP = {0.f,0.f,0.f,0.f}, accG = {0.f,0.f,0.f,0.f};
    floatx4 accQ = {0.f,0.f,0.f,0.f}, accS = {0.f,0.f,0.f,0.f};
    float csl = 0.f;

    uint4 nKh = kCh[(size_t)c0 * 64 + lane];
    uint4 nKl = kCl[(size_t)c0 * 64 + lane];
    uint4 nEh = eBh[(size_t)c0 * 64 + lane];
    uint4 nEl = eBl[(size_t)c0 * 64 + lane];
    float kn[8], vn[8];
    {
        const size_t base = ((size_t)(c0 * 32 + rowoff)) * DM + d;
        #pragma unroll
        for (int e = 0; e < 8; ++e) {
            kn[e] = k[base + (size_t)(e * DM)];
            vn[e] = v[base + (size_t)(e * DM)];
        }
    }

    for (int it = 0; it < 16; ++it) {
        const int c = c0 + it;
        const uint4 aKh = nKh, aKl = nKl, aEh = nEh, aEl = nEl;
        float kc[8], vc[8];
        #pragma unroll
        for (int e = 0; e < 8; ++e) { kc[e] = kn[e]; vc[e] = vn[e]; }

        if (it + 1 < 16) {
            const int cn = c + 1;
            nKh = kCh[(size_t)cn * 64 + lane];
            nKl = kCl[(size_t)cn * 64 + lane];
            nEh = eBh[(size_t)cn * 64 + lane];
            nEl = eBl[(size_t)cn * 64 + lane];
            const size_t base = ((size_t)(cn * 32 + rowoff)) * DM + d;
            #pragma unroll
            for (int e = 0; e < 8; ++e) {
                kn[e] = k[base + (size_t)(e * DM)];
                vn[e] = v[base + (size_t)(e * DM)];
            }
        }

        U4S8 kfh, kfl, vfh, vfl, uKh, uKl, uEh, uEl;
        SPLIT_PAIR(kc[0], kc[1], kfh.u[0], kfl.u[0]);
        SPLIT_PAIR(kc[2], kc[3], kfh.u[1], kfl.u[1]);
        SPLIT_PAIR(kc[4], kc[5], kfh.u[2], kfl.u[2]);
        SPLIT_PAIR(kc[6], kc[7], kfh.u[3], kfl.u[3]);
        SPLIT_PAIR(vc[0], vc[1], vfh.u[0], vfl.u[0]);
        SPLIT_PAIR(vc[2], vc[3], vfh.u[1], vfl.u[1]);
        SPLIT_PAIR(vc[4], vc[5], vfh.u[2], vfl.u[2]);
        SPLIT_PAIR(vc[6], vc[7], vfh.u[3], vfl.u[3]);
        csl += kc[0] + kc[1] + kc[2] + kc[3] + kc[4] + kc[5] + kc[6] + kc[7];
        uKh.u4 = aKh; uKl.u4 = aKl; uEh.u4 = aEh; uEl.u4 = aEl;

        accP = __builtin_amdgcn_mfma_f32_16x16x32_bf16(uKh.s8, vfh.s8, accP, 0, 0, 0);
        accP = __builtin_amdgcn_mfma_f32_16x16x32_bf16(uKh.s8, vfl.s8, accP, 0, 0, 0);
        accP = __builtin_amdgcn_mfma_f32_16x16x32_bf16(uKl.s8, vfh.s8, accP, 0, 0, 0);
        accG = __builtin_amdgcn_mfma_f32_16x16x32_bf16(uEh.s8, kfh.s8, accG, 0, 0, 0);
        accG = __builtin_amdgcn_mfma_f32_16x16x32_bf16(uEh.s8, kfl.s8, accG, 0, 0, 0);
        accG = __builtin_amdgcn_mfma_f32_16x16x32_bf16(uEl.s8, kfh.s8, accG, 0, 0, 0);
        accQ = __builtin_amdgcn_mfma_f32_16x16x32_bf16(uKh.s8, kfh.s8, accQ, 0, 0, 0);
        accS = __builtin_amdgcn_mfma_f32_16x16x32_bf16(uKh.s8, uKh.s8, accS, 0, 0, 0);
    }

    // flush: acc D[row=r][col=d-local]; row=(lane>>4)*4+j, col=lane&15
    const int r0 = (lane >> 4) * 4;
    #pragma unroll
    for (int j = 0; j < 4; ++j) {
        atomicAdd(P1 + (size_t)d * RK + r0 + j, accP[j]);
        atomicAdd(G2 + (size_t)d * RK + r0 + j, accG[j]);
        atomicAdd(Q  + (size_t)d * RK + r0 + j, accQ[j]);
    }
    if (dgrp == 0 && w == 0) {
        #pragma unroll
        for (int j = 0; j < 4; ++j)
            atomicAdd(S2 + (r0 + j) * RK + (lane & 15), accS[j]);
    }
    csl += __shfl_xor(csl, 16);
    csl += __shfl_xor(csl, 32);
    if ((lane >> 4) == 0) atomicAdd(colsum + d, csl);
}

// ---------------------------------------------------------------------------
// k_ro: ro[n,d] = 0.1*kC[n,:].B[d,:] (+ k*D if flag). Pure streaming write.
// 512 blocks (2 d-slabs x 256 chunks of 64 rows) x 256 thr, thread owns 4 d.
// ---------------------------------------------------------------------------
__global__ __launch_bounds__(256) void k_ro(
    const float* __restrict__ k, const float* __restrict__ B,
    const float* __restrict__ Dd, const float* __restrict__ kC_g,
    const int* __restrict__ flag, float* __restrict__ ro)
{
    __shared__ float kCch[64 * 16];
    const int t = threadIdx.x;
    const int slab = blockIdx.x & 1;
    const int chunk = blockIdx.x >> 1;
    const int d0 = slab * 1024 + t * 4;
    const int row0 = chunk * 64;
    const int dnz = *flag;

    float Breg[4][16], Dreg[4];
    #pragma unroll
    for (int i = 0; i < 4; ++i) {
        #pragma unroll
        for (int q = 0; q < 4; ++q) {
            const float4 b4 = *(const float4*)(B + (size_t)(d0 + i) * RK + q * 4);
            Breg[i][q*4+0] = b4.x; Breg[i][q*4+1] = b4.y;
            Breg[i][q*4+2] = b4.z; Breg[i][q*4+3] = b4.w;
        }
        Dreg[i] = Dd[d0 + i];
    }
    *(float4*)&kCch[t * 4] = *(const float4*)(kC_g + (size_t)row0 * RK + t * 4);
    __syncthreads();

    float4 k0 = make_float4(0.f,0.f,0.f,0.f), k1 = k0;
    if (dnz) {
        k0 = *(const float4*)(k + (size_t)row0 * DM + d0);
        k1 = *(const float4*)(k + (size_t)(row0 + 1) * DM + d0);
    }

    for (int rr = 0; rr < 64; ++rr) {
        const int n = row0 + rr;
        const float4 kc4 = k0;
        if (dnz) {
            const int np = row0 + ((rr + 2 < 64) ? rr + 2 : 63);
            k0 = k1; k1 = *(const float4*)(k + (size_t)np * DM + d0);
        }
        float kcr[16];
        #pragma unroll
        for (int q = 0; q < 4; ++q) {
            const float4 c4 = *(const float4*)&kCch[rr * 16 + q * 4];
            kcr[q*4+0] = c4.x; kcr[q*4+1] = c4.y; kcr[q*4+2] = c4.z; kcr[q*4+3] = c4.w;
        }
        float roa[4];
        const float ka4[4] = {kc4.x, kc4.y, kc4.z, kc4.w};
        #pragma unroll
        for (int i = 0; i < 4; ++i) {
            float s = 0.f;
            #pragma unroll
            for (int r = 0; r < 16; ++r) s += kcr[r] * Breg[i][r];
            roa[i] = SCALEc * s;
            if (dnz) roa[i] += ka4[i] * Dreg[i];
        }
        *(float4*)(ro + (size_t)n * DM + d0) = make_float4(roa[0], roa[1], roa[2], roa[3]);
    }
}

// ---------------------------------------------------------------------------
// k_ln: k_mean = colsum/N; h1 = LayerNorm(k_mean)*gamma + beta.
// ---------------------------------------------------------------------------
__global__ __launch_bounds__(256) void k_ln(
    const float* __restrict__ colsum,
    const float* __restrict__ gam, const float* __restrict__ bet,
    float* __restrict__ h1)
{
    __shared__ float red[256];
    __shared__ float mu_sh, var_sh;
    const int t = threadIdx.x;
    float x[8];
    float s = 0.f;
    #pragma unroll
    for (int i = 0; i < 8; ++i) {
        x[i] = colsum[t + 256 * i] * (1.0f / (float)NROWS);
        s += x[i];
    }
    red[t] = s; __syncthreads();
    for (int off = 128; off > 0; off >>= 1) {
        if (t < off) red[t] += red[t + off];
        __syncthreads();
    }
    if (t == 0) mu_sh = red[0] * (1.0f / (float)DM);
    __syncthreads();
    const float mu = mu_sh;
    float s2 = 0.f;
    #pragma unroll
    for (int i = 0; i < 8; ++i) { const float dd = x[i] - mu; s2 += dd * dd; }
    __syncthreads();
    red[t] = s2; __syncthreads();
    for (int off = 128; off > 0; off >>= 1) {
        if (t < off) red[t] += red[t + off];
        __syncthreads();
    }
    if (t == 0) var_sh = red[0] * (1.0f / (float)DM);
    __syncthreads();
    const float rstd = rsqrtf(var_sh + LNEPS);
    #pragma unroll
    for (int i = 0; i < 8; ++i) {
        const int d = t + 256 * i;
        h1[d] = (x[i] - mu) * rstd * gam[d] + bet[d];
    }
}

// ---------------------------------------------------------------------------
// k_gemv: h2[i] = silu(h1 . W1[i,:] + b1[i]). 512 blocks x 256 (wave/row).
// ---------------------------------------------------------------------------
__global__ __launch_bounds__(256) void k_gemv(
    const float* __restrict__ h1, const float* __restrict__ W1,
    const float* __restrict__ b1, float* __restrict__ h2)
{
    const int t = threadIdx.x;
    const int lane = t & 63;
    const int w = t >> 6;
    const int row = blockIdx.x * 4 + w;
    const float* wr = W1 + (size_t)row * DM;
    float s = 0.f;
    #pragma unroll
    for (int j = 0; j < 8; ++j) {
        const float4 a = *(const float4*)(wr + j * 256 + lane * 4);
        const float4 b = *(const float4*)(h1 + j * 256 + lane * 4);
        s += a.x * b.x + a.y * b.y + a.z * b.z + a.w * b.w;
    }
    #pragma unroll
    for (int off = 32; off > 0; off >>= 1) s += __shfl_down(s, off);
    if (lane == 0) {
        const float val = s + b1[row];
        h2[row] = val / (1.0f + expf(-val));
    }
}

// ---------------------------------------------------------------------------
// k_alpha: alpha = sigmoid(h2 . W2 + b2).
// ---------------------------------------------------------------------------
__global__ __launch_bounds__(256) void k_alpha(
    const float* __restrict__ h2, const float* __restrict__ W2,
    const float* __restrict__ b2,
    float* __restrict__ alpha_ws, float* __restrict__ out_alpha)
{
    __shared__ float red[256];
    const int t = threadIdx.x;
    float s = 0.f;
    for (int i = t; i < DM; i += 256) s += h2[i] * W2[i];
    red[t] = s; __syncthreads();
    for (int off = 128; off > 0; off >>= 1) {
        if (t < off) red[t] += red[t + off];
        __syncthreads();
    }
    if (t == 0) {
        const float logit = red[0] + b2[0];
        const float a = 1.0f / (1.0f + expf(-logit));
        alpha_ws[0] = a;
        out_alpha[0] = a;
    }
}

// ---------------------------------------------------------------------------
// k_update: G1 = P1 - 0.1*B@S2 - D o Q; grads, momentum, B/C update.
// ---------------------------------------------------------------------------
__global__ __launch_bounds__(256) void k_update(
    const float* __restrict__ B, const float* __restrict__ C,
    const float* __restrict__ Dd,
    const float* __restrict__ S_B, const float* __restrict__ S_C,
    const float* __restrict__ P1, const float* __restrict__ G2,
    const float* __restrict__ Q, const float* __restrict__ S2,
    const float* __restrict__ CtC, const float* __restrict__ BtB,
    const float* __restrict__ alpha_ws,
    float* __restrict__ outB, float* __restrict__ outC,
    float* __restrict__ outSB, float* __restrict__ outSC)
{
    const int idx = blockIdx.x * 256 + threadIdx.x;   // [0, 32768)
    const int d = idx >> 4, r = idx & 15;
    const float alpha = alpha_ws[0];

    float Brow[16], Crow[16];
    #pragma unroll
    for (int q = 0; q < 4; ++q) {
        const float4 b4 = *(const float4*)(B + (size_t)d * RK + q * 4);
        const float4 c4 = *(const float4*)(C + (size_t)d * RK + q * 4);
        Brow[q*4+0] = b4.x; Brow[q*4+1] = b4.y; Brow[q*4+2] = b4.z; Brow[q*4+3] = b4.w;
        Crow[q*4+0] = c4.x; Crow[q*4+1] = c4.y; Crow[q*4+2] = c4.z; Crow[q*4+3] = c4.w;
    }
    float bc = 0.f, cb = 0.f, bs2 = 0.f;
    #pragma unroll
    for (int a = 0; a < 16; ++a) {
        bc  += Brow[a] * CtC[a * RK + r];
        cb  += Crow[a] * BtB[a * RK + r];
        bs2 += Brow[a] * S2[a * RK + r];
    }
    const float Ddv = Dd[d];
    const float invN = 1.0f / (float)NROWS;
    const float G1v = P1[idx] - SCALEc * bs2 - Ddv * Q[idx];
    const float gradB = -G1v * invN + L2c * (SCALEc * bc + Ddv * Crow[r]);
    const float gradC = -G2[idx] * invN + L2c * (SCALEc * cb + Ddv * Brow[r]);
    const float sB = MOMc * S_B[idx] - LRc * gradB;
    const float sC = MOMc * S_C[idx] - LRc * gradC;
    outSB[idx] = sB;
    outSC[idx] = sC;
    outB[idx] = (1.0f - alpha) * B[idx] + sB;
    outC[idx] = (1.0f - alpha) * C[idx] + sC;
}

// ---------------------------------------------------------------------------
extern "C" void kernel_launch(void* const* d_in, const int* in_sizes, int n_in,
                              void* d_out, int out_size, void* d_ws, size_t ws_size,
                              hipStream_t stream)
{
    const float* k   = (const float*)d_in[0];
    const float* v   = (const float*)d_in[1];
    const float* B   = (const float*)d_in[2];
    const float* C   = (const float*)d_in[3];
    const float* Dd  = (const float*)d_in[4];
    const float* S_B = (const float*)d_in[5];
    const float* S_C = (const float*)d_in[6];
    const float* gam = (const float*)d_in[7];
    const float* bet = (const float*)d_in[8];
    const float* W1  = (const float*)d_in[9];
    const float* b1  = (const float*)d_in[10];
    const float* W2  = (const float*)d_in[11];
    const float* b2  = (const float*)d_in[12];

    float* out      = (float*)d_out;
    float* ro       = out;                                  // [N, D]
    float* outB     = out + (size_t)NROWS * DM;
    float* outC     = outB + (size_t)DM * RK;
    float* outSB    = outC + (size_t)DM * RK;
    float* outSC    = outSB + (size_t)DM * RK;
    float* outAlpha = outSC + (size_t)DM * RK;

    float* ws = (float*)d_ws;
    float* kC_g   = ws;                                     // 262144
    float* vB_g   = kC_g + (size_t)NROWS * RK;              // 262144
    float* eB_g   = vB_g + (size_t)NROWS * RK;              // 262144 (kDB -> errB)
    float* P1     = eB_g + (size_t)NROWS * RK;              // 32768 -- zero start
    float* G2     = P1 + (size_t)DM * RK;                   // 32768
    float* Q      = G2 + (size_t)DM * RK;                   // 32768
    float* S2     = Q + (size_t)DM * RK;                    // 256
    float* CtC    = S2 + 256;                               // 256
    float* BtB    = CtC + 256;                              // 256
    float* colsum = BtB + 256;                              // 2048 -- zero end
    float* h1     = colsum + DM;                            // 2048
    float* h2     = h1 + DM;                                // 2048
    uint4* Cpk    = (uint4*)(h2 + DM);                      // 4096 uint4
    uint4* Bpk    = Cpk + 4096;
    uint4* DBpk   = Bpk + 4096;
    uint4* kCh    = DBpk + 4096;                            // 32768 uint4 each
    uint4* kCl    = kCh + 32768;
    uint4* eBh    = kCl + 32768;
    uint4* eBl    = eBh + 32768;
    float* alphaW = (float*)(eBl + 32768);
    int*   flag   = (int*)(alphaW + 1);

    // zero P1..colsum: 3*32768 + 3*256 + 2048 = 101120 floats
    hipMemsetAsync(P1, 0, (size_t)101120 * sizeof(float), stream);

    hipLaunchKernelGGL(k_prep, dim3(33), dim3(256), 0, stream,
                       B, C, Dd, BtB, CtC, Cpk, Bpk, DBpk, flag);
    hipLaunchKernelGGL(k_A, dim3(1024), dim3(256), 0, stream,
                       k, v, Cpk, Bpk, DBpk, flag, kC_g, vB_g, eB_g);
    hipLaunchKernelGGL(k_mid, dim3(64), dim3(256), 0, stream,
                       kC_g, vB_g, eB_g, BtB, flag);
    hipLaunchKernelGGL(k_pack, dim3(128), dim3(256), 0, stream,
                       kC_g, eB_g, kCh, kCl, eBh, eBl);
    hipLaunchKernelGGL(k_T, dim3(1024), dim3(256), 0, stream,
                       k, v, kCh, kCl, eBh, eBl, P1, G2, Q, S2, colsum);
    hipLaunchKernelGGL(k_ro, dim3(512), dim3(256), 0, stream,
                       k, B, Dd, kC_g, flag, ro);
    hipLaunchKernelGGL(k_ln, dim3(1), dim3(256), 0, stream, colsum, gam, bet, h1);
    hipLaunchKernelGGL(k_gemv, dim3(512), dim3(256), 0, stream, h1, W1, b1, h2);
    hipLaunchKernelGGL(k_alpha, dim3(1), dim3(256), 0, stream, h2, W2, b2, alphaW, outAlpha);
    hipLaunchKernelGGL(k_update, dim3(128), dim3(256), 0, stream,
                       B, C, Dd, S_B, S_C, P1, G2, Q, S2, CtC, BtB, alphaW,
                       outB, outC, outSB, outSC);
}